// Round 4
// baseline (285.604 us; speedup 1.0000x reference)
//
#include <hip/hip_runtime.h>
#include <hip/hip_bf16.h>

#define L_ 64
#define B_ 32
#define S_ 64
#define D_ 512
#define V_ 32000
#define NL_ 2

typedef __attribute__((ext_vector_type(8))) short bf16x8;
typedef __attribute__((ext_vector_type(4))) float f32x4;

static __device__ __forceinline__ short f2bf(float f) {
  union { float f; unsigned u; } x; x.f = f;
  unsigned r = (x.u + 0x7FFFu + ((x.u >> 16) & 1u)) >> 16;
  return (short)r;
}

#define GLOAD_LDS16(g, l)                                                     \
  __builtin_amdgcn_global_load_lds(                                           \
      (const __attribute__((address_space(1))) void*)(g),                     \
      (__attribute__((address_space(3))) void*)(l), 16, 0, 0)

// ---------------- embedding gather: x[l,b,d] = tab[tok[l,b], d] -------------
__global__ void embed_kernel(const int* __restrict__ tok, const float* __restrict__ tab,
                             float* __restrict__ xf, short* __restrict__ xb) {
  int i = blockIdx.x * 256 + threadIdx.x;  // < L*B*D = 1048576
  int d = i & (D_ - 1);
  int lb = i >> 9;
  float v = tab[(size_t)tok[lb] * D_ + d];
  xf[i] = v;
  xb[i] = f2bf(v);
}

// ------------- f32 [K,N] -> bf16 [N,K] transpose (LDS-tiled) ----------------
__global__ void transpose_f32_bf16(const float* __restrict__ in, short* __restrict__ out,
                                   int K, int N) {
  __shared__ float tile[32][33];
  int x = blockIdx.x * 32 + threadIdx.x;  // N index
  int y0 = blockIdx.y * 32;               // K base
  for (int j = threadIdx.y; j < 32; j += 8) {
    int y = y0 + j;
    tile[j][threadIdx.x] = (x < N && y < K) ? in[(size_t)y * N + x] : 0.f;
  }
  __syncthreads();
  int xo = y0 + threadIdx.x;              // K index
  int yo0 = blockIdx.x * 32;              // N base
  for (int j = threadIdx.y; j < 32; j += 8) {
    int yo = yo0 + j;
    if (yo < N && xo < K) out[(size_t)yo * K + xo] = f2bf(tile[threadIdx.x][j]);
  }
}

// ============ 128x128 2-phase GEMM (known-good; SRU + attn GEMMs) ===========
// MODE 0: write f32 C[M,N]
// MODE 1: write bf16 tanh(C)[M,N]
#define BM 128
#define BN 128
#define BK 64

template <int MODE>
__global__ __launch_bounds__(256) void gemm_kernel(
    const short* __restrict__ A, const short* __restrict__ BT,
    void* __restrict__ Cptr, const float* __restrict__ bias,
    int M, int N, int K, int nbm) {
  const int nwg = gridDim.x;
  const int qc = nwg >> 3;
  const int bid = blockIdx.x;
  const int wg = (bid & 7) * qc + (bid >> 3);
  const int bm = wg % nbm;
  const int bn = wg / nbm;

  __shared__ __align__(16) short la[2][BM * BK];
  __shared__ __align__(16) short lb[2][BN * BK];
  const int tid = threadIdx.x;
  const int wave = tid >> 6, lane = tid & 63;
  const int wm = (wave >> 1) * 64, wn = (wave & 1) * 64;

  f32x4 acc[4][4] = {};

  const int lrow = lane >> 3;
  const int lslot = lane & 7;
  const short* Abase = A + (size_t)(bm * BM) * K;
  const short* Bbase = BT + (size_t)(bn * BN) * K;

  auto stage = [&](int buf, int k0) {
#pragma unroll
    for (int c = 0; c < 4; ++c) {
      int chunk = wave * 4 + c;
      int row = chunk * 8 + lrow;
      int slot = lslot ^ (row & 7);
      GLOAD_LDS16(Abase + (size_t)row * K + k0 + slot * 8, &la[buf][chunk * 512]);
      GLOAD_LDS16(Bbase + (size_t)row * K + k0 + slot * 8, &lb[buf][chunk * 512]);
    }
  };

  stage(0, 0);
  __syncthreads();

  const int nt = K / BK;
  int cur = 0;
  for (int t = 0; t < nt; ++t) {
    if (t + 1 < nt) stage(cur ^ 1, (t + 1) * BK);
#pragma unroll
    for (int kk = 0; kk < 2; ++kk) {
      bf16x8 af[4], bfr[4];
#pragma unroll
      for (int mi = 0; mi < 4; ++mi) {
        int row = wm + mi * 16 + (lane & 15);
        int slot = (kk * 4 + (lane >> 4)) ^ (row & 7);
        af[mi] = *(const bf16x8*)&la[cur][row * 64 + slot * 8];
      }
#pragma unroll
      for (int ni = 0; ni < 4; ++ni) {
        int row = wn + ni * 16 + (lane & 15);
        int slot = (kk * 4 + (lane >> 4)) ^ (row & 7);
        bfr[ni] = *(const bf16x8*)&lb[cur][row * 64 + slot * 8];
      }
#pragma unroll
      for (int mi = 0; mi < 4; ++mi)
#pragma unroll
        for (int ni = 0; ni < 4; ++ni)
          acc[mi][ni] = __builtin_amdgcn_mfma_f32_16x16x32_bf16(
              af[mi], bfr[ni], acc[mi][ni], 0, 0, 0);
    }
    __syncthreads();
    cur ^= 1;
  }

  const int cl = lane & 15;
  const int rl = (lane >> 4) * 4;
#pragma unroll
  for (int mi = 0; mi < 4; ++mi) {
#pragma unroll
    for (int ni = 0; ni < 4; ++ni) {
      int c = bn * BN + wn + ni * 16 + cl;
      int r0 = bm * BM + wm + mi * 16 + rl;
#pragma unroll
      for (int j = 0; j < 4; ++j) {
        int r = r0 + j;
        float v = acc[mi][ni][j];
        if (MODE == 0) {
          ((float*)Cptr)[(size_t)r * N + c] = v;
        } else {
          ((short*)Cptr)[(size_t)r * N + c] = f2bf(tanhf(v));
        }
      }
    }
  }
}

// ===== 256x256 BK=32 ring-of-4 counted-vmcnt GEMM (the big V GEMM) ==========
// 8 waves (2M x 4N), per-wave 128x64 output, acc[8][4] f32x4.
// LDS: 4 K-tile slots x (A 16KB + B 16KB) = 128 KiB. Each iteration stages
// tile t+3, computes tile t, then s_waitcnt vmcnt(8); s_barrier (tile t+1
// guaranteed landed, tiles t+2/t+3 stay in flight -> no drain-to-0 stall).
// Slot (t+3)&3 == (t-1)&3 was fully read in iter t-1 (barrier) -> race-free.
// LDS line layout: 2 K-rows (64B each) per 128B line; slot8 within line =
// ((row&1)*4 + kq) ^ ((row>>1)&7)  -> 2 lanes/bank-quad on all frag reads.
// Inverse permutation applied to the GLOBAL source; LDS dest stays linear.
// MODE 2: write f32 C[row-remap (l*B+b)->(b*L+l)][N] + bias[n]
#define BM2 256
#define BN2 256
#define BK2 32

template <int MODE>
__global__ __launch_bounds__(512, 2) void gemm256_kernel(
    const short* __restrict__ A, const short* __restrict__ BT,
    void* __restrict__ Cptr, const float* __restrict__ bias,
    int M, int N, int K, int nbm) {
  const int nwg = gridDim.x;
  const int qc = nwg >> 3;
  const int bid = blockIdx.x;
  const int wg = (bid & 7) * qc + (bid >> 3);
  const int bm = wg % nbm;
  const int bn = wg / nbm;

  __shared__ __align__(16) short la[4][BM2 * BK2];  // 4 x 16 KB
  __shared__ __align__(16) short lb[4][BN2 * BK2];  // 4 x 16 KB

  const int tid = threadIdx.x;
  const int wave = tid >> 6, lane = tid & 63;
  const int wmb = (wave >> 2) * 128;  // wave M base within tile
  const int wnb = (wave & 3) * 64;    // wave N base within tile

  f32x4 acc[8][4] = {};

  const short* Abase = A + (size_t)(bm * BM2) * K;
  const short* Bbase = BT + (size_t)(bn * BN2) * K;
  const int nt = K / BK2;  // requires nt >= 4

  auto stage = [&](int slot, int t) {
    const int k0 = t * BK2;
#pragma unroll
    for (int i = 0; i < 2; ++i) {
      int p = i * 64 + (tid >> 3);
      int u = (tid & 7) ^ (p & 7);
      int row = 2 * p + (u >> 2);
      int kq = u & 3;
      GLOAD_LDS16(Abase + (size_t)row * K + k0 + kq * 8, &la[slot][i * 4096 + tid * 8]);
    }
#pragma unroll
    for (int i = 0; i < 2; ++i) {
      int p = i * 64 + (tid >> 3);
      int u = (tid & 7) ^ (p & 7);
      int row = 2 * p + (u >> 2);
      int kq = u & 3;
      GLOAD_LDS16(Bbase + (size_t)row * K + k0 + kq * 8, &lb[slot][i * 4096 + tid * 8]);
    }
  };

  stage(0, 0);
  stage(1, 1);
  stage(2, 2);
  asm volatile("s_waitcnt vmcnt(8)\n\ts_barrier" ::: "memory");  // tile 0 landed

  const int kq = lane >> 4;  // 0..3 -> k = kq*8..kq*8+7
  const int fr = lane & 15;
  int aoff[8], boff[4];
#pragma unroll
  for (int mi = 0; mi < 8; ++mi) {
    int r = wmb + mi * 16 + fr;
    aoff[mi] = (r >> 1) * 64 + (((((r & 1) << 2) | kq) ^ ((r >> 1) & 7)) << 3);
  }
#pragma unroll
  for (int ni = 0; ni < 4; ++ni) {
    int r = wnb + ni * 16 + fr;
    boff[ni] = (r >> 1) * 64 + (((((r & 1) << 2) | kq) ^ ((r >> 1) & 7)) << 3);
  }

  for (int t = 0; t < nt; ++t) {
    const int cur = t & 3;
    if (t + 3 < nt) stage((t + 3) & 3, t + 3);
    bf16x8 bfrag[4];
#pragma unroll
    for (int ni = 0; ni < 4; ++ni) bfrag[ni] = *(const bf16x8*)&lb[cur][boff[ni]];
#pragma unroll
    for (int mi = 0; mi < 8; ++mi) {
      bf16x8 af = *(const bf16x8*)&la[cur][aoff[mi]];
#pragma unroll
      for (int ni = 0; ni < 4; ++ni)
        acc[mi][ni] = __builtin_amdgcn_mfma_f32_16x16x32_bf16(af, bfrag[ni], acc[mi][ni], 0, 0, 0);
    }
    if (t < nt - 1) {
      if (t + 3 < nt) {
        asm volatile("s_waitcnt vmcnt(8)\n\ts_barrier" ::: "memory");
      } else if (t + 2 < nt) {
        asm volatile("s_waitcnt vmcnt(4)\n\ts_barrier" ::: "memory");
      } else {
        asm volatile("s_waitcnt vmcnt(0)\n\ts_barrier" ::: "memory");
      }
    }
  }

  // epilogue
#pragma unroll
  for (int mi = 0; mi < 8; ++mi) {
#pragma unroll
    for (int ni = 0; ni < 4; ++ni) {
      int c = bn * BN2 + wnb + ni * 16 + fr;
      int r0 = bm * BM2 + wmb + mi * 16 + (lane >> 4) * 4;
      float bs = (MODE == 2) ? bias[c] : 0.f;
#pragma unroll
      for (int j = 0; j < 4; ++j) {
        int r = r0 + j;
        float v = acc[mi][ni][j];
        if (MODE == 2) {
          int b = r & 31, l = r >> 5;
          ((float*)Cptr)[(size_t)(b * L_ + l) * N + c] = v + bs;
        } else {
          ((float*)Cptr)[(size_t)r * N + c] = v;
        }
      }
    }
  }
}

// ---------------- SRU scan: per (b,d) lane, 8-step chunked prefetch ---------
__global__ void sru_scan_kernel(const float* __restrict__ U, const float* __restrict__ bvec,
                                const float* __restrict__ xin, const float* __restrict__ c0,
                                float* __restrict__ hf, short* __restrict__ hb,
                                float* __restrict__ clast) {
  int idx = blockIdx.x * 64 + threadIdx.x;  // < B*D = 16384
  int b = idx >> 9, d = idx & 511;
  float c = c0[idx];
  const float bfb = bvec[d], brb = bvec[512 + d];
  const float* Ub = U + (size_t)b * 1536 + d;
  const float* Xb = xin + (size_t)b * 512 + d;

  for (int l0 = 0; l0 < L_; l0 += 8) {
    float z[8], fp[8], rp[8], xv[8];
#pragma unroll
    for (int j = 0; j < 8; ++j) {
      size_t u = (size_t)(l0 + j) * B_ * 1536;
      z[j] = Ub[u];
      fp[j] = Ub[u + 512];
      rp[j] = Ub[u + 1024];
      xv[j] = Xb[(size_t)(l0 + j) * B_ * 512];
    }
#pragma unroll
    for (int j = 0; j < 8; ++j) {
      float f = 1.f / (1.f + expf(-(fp[j] + bfb)));
      float r = 1.f / (1.f + expf(-(rp[j] + brb)));
      c = f * c + (1.f - f) * z[j];
      float h = r * tanhf(c) + (1.f - r) * xv[j];
      size_t o = ((size_t)(l0 + j) * B_ + b) * 512 + d;
      hf[o] = h;
      hb[o] = f2bf(h);
    }
  }
  clast[idx] = c;
}

// ------ fused attention: scores + softmax + ctx + concat, per (l,b) row -----
__global__ __launch_bounds__(256) void attn_fused_kernel(
    const float* __restrict__ x, const float* __restrict__ enc,
    const short* __restrict__ xq, short* __restrict__ cat) {
  __shared__ float q[512];
  __shared__ float al[64];
  int r = blockIdx.x;       // l*B + b
  int b = r & (B_ - 1);
  int tid = threadIdx.x;
  int wave = tid >> 6, lane = tid & 63;
  for (int d = tid; d < 512; d += 256) {
    q[d] = x[(size_t)r * 512 + d];
    cat[(size_t)r * 1024 + 512 + d] = xq[(size_t)r * 512 + d];
  }
  __syncthreads();
#pragma unroll
  for (int si = 0; si < 16; ++si) {
    int s = wave * 16 + si;
    const float* m = enc + ((size_t)s * B_ + b) * 512;
    float a = 0.f;
#pragma unroll
    for (int k = 0; k < 8; ++k) a += q[lane + k * 64] * m[lane + k * 64];
    for (int o = 32; o > 0; o >>= 1) a += __shfl_xor(a, o);
    if (lane == 0) al[s] = a;
  }
  __syncthreads();
  if (tid < 64) {
    float v = al[tid];
    float mx = v;
    for (int o = 32; o > 0; o >>= 1) mx = fmaxf(mx, __shfl_xor(mx, o));
    float e = expf(v - mx);
    float sm = e;
    for (int o = 32; o > 0; o >>= 1) sm += __shfl_xor(sm, o);
    al[tid] = e / sm;
  }
  __syncthreads();
  for (int d = tid; d < 512; d += 256) {
    float acc = 0.f;
#pragma unroll 16
    for (int s = 0; s < S_; ++s) acc += al[s] * enc[((size_t)s * B_ + b) * 512 + d];
    cat[(size_t)r * 1024 + d] = f2bf(acc);
  }
}

extern "C" void kernel_launch(void* const* d_in, const int* in_sizes, int n_in,
                              void* d_out, int out_size, void* d_ws, size_t ws_size,
                              hipStream_t stream) {
  const int* rnn = (const int*)d_in[0];
  const float* h0 = (const float*)d_in[1];
  const float* enc = (const float*)d_in[2];
  const float* tab = (const float*)d_in[3];
  const float* sruW = (const float*)d_in[4];
  const float* srub = (const float*)d_in[5];
  const float* attnW = (const float*)d_in[6];
  const float* outW = (const float*)d_in[7];
  const float* outb = (const float*)d_in[8];
  float* out = (float*)d_out;

  char* ws = (char*)d_ws;
  size_t off = 0;
  auto alloc = [&](size_t bytes) {
    char* p = ws + off;
    off += (bytes + 255) & ~(size_t)255;
    return p;
  };
  float* xf = (float*)alloc(4ull * 2048 * 512);
  float* xf2 = (float*)alloc(4ull * 2048 * 512);
  short* xb = (short*)alloc(2ull * 2048 * 512);
  float* U = (float*)alloc(4ull * 2048 * 1536);
  short* WTs = (short*)alloc(2ull * 2 * 1536 * 512);
  short* WTa = (short*)alloc(2ull * 512 * 1024);
  short* WTo = (short*)alloc(2ull * 32000 * 512);
  short* cat = (short*)alloc(2ull * 2048 * 1024);
  short* ah = (short*)alloc(2ull * 2048 * 512);

  dim3 tb(32, 8);
  for (int l = 0; l < NL_; ++l)
    transpose_f32_bf16<<<dim3(48, 16), tb, 0, stream>>>(
        sruW + (size_t)l * 512 * 1536, WTs + (size_t)l * 1536 * 512, 512, 1536);
  transpose_f32_bf16<<<dim3(16, 32), tb, 0, stream>>>(attnW, WTa, 1024, 512);
  transpose_f32_bf16<<<dim3(1000, 16), tb, 0, stream>>>(outW, WTo, 512, 32000);

  embed_kernel<<<4096, 256, 0, stream>>>(rnn, tab, xf, xb);

  float* hidden_out = out + (size_t)B_ * L_ * V_;

  // layer 0: x(=embed) -> h in xf2/xb
  gemm_kernel<0><<<192, 256, 0, stream>>>(xb, WTs, U, nullptr, 2048, 1536, 512, 16);
  sru_scan_kernel<<<256, 64, 0, stream>>>(U, srub, xf, h0, xf2, xb, hidden_out);
  // layer 1: h1 -> final h in xf/xb
  gemm_kernel<0><<<192, 256, 0, stream>>>(xb, WTs + 1536 * 512, U, nullptr, 2048, 1536, 512, 16);
  sru_scan_kernel<<<256, 64, 0, stream>>>(U, srub + 1024, xf2, h0 + B_ * D_, xf, xb,
                                          hidden_out + B_ * D_);

  // fused attention: scores+softmax+ctx+concat
  attn_fused_kernel<<<2048, 256, 0, stream>>>(xf, enc, xb, cat);

  // attn_h = tanh(concat @ attn_W) as bf16
  gemm_kernel<1><<<64, 256, 0, stream>>>(cat, WTa, ah, nullptr, 2048, 512, 1024, 16);
  // output = attn_h @ out_W + out_b, remapped to [B,L,V]  (256^2 ring kernel)
  gemm256_kernel<2><<<1000, 512, 0, stream>>>(ah, WTo, out, outb, 2048, 32000, 512, 8);
}

// Round 5
// 244.735 us; speedup vs baseline: 1.1670x; 1.1670x over previous
//
#include <hip/hip_runtime.h>
#include <hip/hip_bf16.h>

#define L_ 64
#define B_ 32
#define S_ 64
#define D_ 512
#define V_ 32000
#define NL_ 2

typedef __attribute__((ext_vector_type(8))) short bf16x8;
typedef __attribute__((ext_vector_type(4))) float f32x4;

static __device__ __forceinline__ short f2bf(float f) {
  union { float f; unsigned u; } x; x.f = f;
  unsigned r = (x.u + 0x7FFFu + ((x.u >> 16) & 1u)) >> 16;
  return (short)r;
}

#define GLOAD_LDS16(g, l)                                                     \
  __builtin_amdgcn_global_load_lds(                                           \
      (const __attribute__((address_space(1))) void*)(g),                     \
      (__attribute__((address_space(3))) void*)(l), 16, 0, 0)

// ===== fused prep: all weight transposes (f32 [K,N] -> bf16 [N,K]) + embed ==
// block ranges: [0,768) WTs L0 | [768,1536) WTs L1 | [1536,2048) WTa
//               [2048,18048) WTo | [18048,22144) embed
__global__ void prep_kernel(const float* __restrict__ sruW, const float* __restrict__ attnW,
                            const float* __restrict__ outW, const int* __restrict__ tok,
                            const float* __restrict__ tab,
                            short* __restrict__ WTs, short* __restrict__ WTa,
                            short* __restrict__ WTo,
                            float* __restrict__ xf, short* __restrict__ xb) {
  int bid = blockIdx.x;
  int tx = threadIdx.x, ty = threadIdx.y;  // (32,8)
  __shared__ float tile[32][33];
  if (bid < 18048) {
    const float* in;
    short* out;
    int K, N, bx, by;
    if (bid < 1536) {
      int l = bid >> 9 >= 1 ? (bid >= 768) : 0;  // placeholder
      l = (bid >= 768) ? 1 : 0;
      int r = bid - l * 768;
      bx = r % 48; by = r / 48; K = 512; N = 1536;
      in = sruW + (size_t)l * 512 * 1536;
      out = WTs + (size_t)l * 1536 * 512;
    } else if (bid < 2048) {
      int r = bid - 1536;
      bx = r % 16; by = r / 16; K = 1024; N = 512;
      in = attnW; out = WTa;
    } else {
      int r = bid - 2048;
      bx = r % 1000; by = r / 1000; K = 512; N = 32000;
      in = outW; out = WTo;
    }
    int x = bx * 32 + tx;
    int y0 = by * 32;
    for (int j = ty; j < 32; j += 8) {
      int y = y0 + j;
      tile[j][tx] = (x < N && y < K) ? in[(size_t)y * N + x] : 0.f;
    }
    __syncthreads();
    int xo = y0 + tx;
    int yo0 = bx * 32;
    for (int j = ty; j < 32; j += 8) {
      int yo = yo0 + j;
      if (yo < N && xo < K) out[(size_t)yo * K + xo] = f2bf(tile[tx][j]);
    }
  } else {
    int i = (bid - 18048) * 256 + ty * 32 + tx;  // < 2048*512
    int d = i & (D_ - 1);
    int lb = i >> 9;
    float v = tab[(size_t)tok[lb] * D_ + d];
    xf[i] = v;
    xb[i] = f2bf(v);
  }
}

// ===== tile-templated 2-phase bf16 MFMA GEMM: C = A[M,K] * BT[N,K]^T ========
// BK fixed 64. Waves arranged WM x WN (WM*WN == 4). XCD-chunked swizzle,
// bm-fastest. Double-buffered LDS; stage(t+1) issued before compute(t).
// MODE 0: f32 C[M,N] | MODE 1: bf16 tanh(C)[M,N]
// MODE 2: f32 C[row-remap (l*B+b)->(b*L+l)][N] + bias[n]
template <int BMt, int BNt, int WM, int WN, int MODE>
__global__ __launch_bounds__(256) void gemm_t(
    const short* __restrict__ A, const short* __restrict__ BT,
    void* __restrict__ Cptr, const float* __restrict__ bias,
    int M, int N, int K, int nbm) {
  constexpr int MI = BMt / WM / 16;
  constexpr int NI = BNt / WN / 16;
  constexpr int ACH = BMt / 8;          // A chunks (8 rows x 64 bf16 = 1KB)
  constexpr int NCH = (BMt + BNt) / 8;  // total chunks
  constexpr int CPW = NCH / 4;          // chunks per wave

  const int nwg = gridDim.x;
  const int qc = nwg >> 3;
  const int bid = blockIdx.x;
  const int wg = (bid & 7) * qc + (bid >> 3);
  const int bm = wg % nbm;
  const int bn = wg / nbm;

  __shared__ __align__(16) short la[2][BMt * 64];
  __shared__ __align__(16) short lb[2][BNt * 64];
  const int tid = threadIdx.x;
  const int wave = tid >> 6, lane = tid & 63;
  const int wm = (wave / WN) * (BMt / WM);
  const int wn = (wave % WN) * (BNt / WN);

  f32x4 acc[MI][NI] = {};

  const int lrow = lane >> 3;
  const int lslot = lane & 7;
  const short* Abase = A + (size_t)(bm * BMt) * K;
  const short* Bbase = BT + (size_t)(bn * BNt) * K;

  auto stage = [&](int buf, int k0) {
#pragma unroll
    for (int c = 0; c < CPW; ++c) {
      int chunk = wave * CPW + c;
      if (chunk < ACH) {
        int row = chunk * 8 + lrow;
        int slot = lslot ^ (row & 7);
        GLOAD_LDS16(Abase + (size_t)row * K + k0 + slot * 8, &la[buf][chunk * 512]);
      } else {
        int bc = chunk - ACH;
        int row = bc * 8 + lrow;
        int slot = lslot ^ (row & 7);
        GLOAD_LDS16(Bbase + (size_t)row * K + k0 + slot * 8, &lb[buf][bc * 512]);
      }
    }
  };

  stage(0, 0);
  __syncthreads();

  const int nt = K / 64;
  int cur = 0;
  for (int t = 0; t < nt; ++t) {
    if (t + 1 < nt) stage(cur ^ 1, (t + 1) * 64);
#pragma unroll
    for (int kk = 0; kk < 2; ++kk) {
      bf16x8 af[MI], bfr[NI];
#pragma unroll
      for (int mi = 0; mi < MI; ++mi) {
        int row = wm + mi * 16 + (lane & 15);
        int slot = (kk * 4 + (lane >> 4)) ^ (row & 7);
        af[mi] = *(const bf16x8*)&la[cur][row * 64 + slot * 8];
      }
#pragma unroll
      for (int ni = 0; ni < NI; ++ni) {
        int row = wn + ni * 16 + (lane & 15);
        int slot = (kk * 4 + (lane >> 4)) ^ (row & 7);
        bfr[ni] = *(const bf16x8*)&lb[cur][row * 64 + slot * 8];
      }
#pragma unroll
      for (int mi = 0; mi < MI; ++mi)
#pragma unroll
        for (int ni = 0; ni < NI; ++ni)
          acc[mi][ni] = __builtin_amdgcn_mfma_f32_16x16x32_bf16(
              af[mi], bfr[ni], acc[mi][ni], 0, 0, 0);
    }
    __syncthreads();
    cur ^= 1;
  }

  const int cl = lane & 15;
  const int rl = (lane >> 4) * 4;
#pragma unroll
  for (int mi = 0; mi < MI; ++mi) {
#pragma unroll
    for (int ni = 0; ni < NI; ++ni) {
      int c = bn * BNt + wn + ni * 16 + cl;
      int r0 = bm * BMt + wm + mi * 16 + rl;
      float bs = (MODE == 2) ? bias[c] : 0.f;
#pragma unroll
      for (int j = 0; j < 4; ++j) {
        int r = r0 + j;
        float v = acc[mi][ni][j];
        if (MODE == 0) {
          ((float*)Cptr)[(size_t)r * N + c] = v;
        } else if (MODE == 1) {
          ((short*)Cptr)[(size_t)r * N + c] = f2bf(tanhf(v));
        } else {
          int b = r & 31, l = r >> 5;
          ((float*)Cptr)[(size_t)(b * L_ + l) * N + c] = v + bs;
        }
      }
    }
  }
}

// ---------------- SRU scan: per (b,d) lane, 8-step chunked prefetch ---------
__global__ void sru_scan_kernel(const float* __restrict__ U, const float* __restrict__ bvec,
                                const float* __restrict__ xin, const float* __restrict__ c0,
                                float* __restrict__ hf, short* __restrict__ hb,
                                float* __restrict__ clast) {
  int idx = blockIdx.x * 64 + threadIdx.x;  // < B*D = 16384
  int b = idx >> 9, d = idx & 511;
  float c = c0[idx];
  const float bfb = bvec[d], brb = bvec[512 + d];
  const float* Ub = U + (size_t)b * 1536 + d;
  const float* Xb = xin + (size_t)b * 512 + d;

  for (int l0 = 0; l0 < L_; l0 += 8) {
    float z[8], fp[8], rp[8], xv[8];
#pragma unroll
    for (int j = 0; j < 8; ++j) {
      size_t u = (size_t)(l0 + j) * B_ * 1536;
      z[j] = Ub[u];
      fp[j] = Ub[u + 512];
      rp[j] = Ub[u + 1024];
      xv[j] = Xb[(size_t)(l0 + j) * B_ * 512];
    }
#pragma unroll
    for (int j = 0; j < 8; ++j) {
      float f = 1.f / (1.f + expf(-(fp[j] + bfb)));
      float r = 1.f / (1.f + expf(-(rp[j] + brb)));
      c = f * c + (1.f - f) * z[j];
      float h = r * tanhf(c) + (1.f - r) * xv[j];
      size_t o = ((size_t)(l0 + j) * B_ + b) * 512 + d;
      hf[o] = h;
      hb[o] = f2bf(h);
    }
  }
  clast[idx] = c;
}

// ------ fused attention: scores + softmax + ctx + concat, per (l,b) row -----
__global__ __launch_bounds__(256) void attn_fused_kernel(
    const float* __restrict__ x, const float* __restrict__ enc,
    const short* __restrict__ xq, short* __restrict__ cat) {
  __shared__ float q[512];
  __shared__ float al[64];
  int r = blockIdx.x;       // l*B + b
  int b = r & (B_ - 1);
  int tid = threadIdx.x;
  int wave = tid >> 6, lane = tid & 63;
  for (int d = tid; d < 512; d += 256) {
    q[d] = x[(size_t)r * 512 + d];
    cat[(size_t)r * 1024 + 512 + d] = xq[(size_t)r * 512 + d];
  }
  __syncthreads();
#pragma unroll
  for (int si = 0; si < 16; ++si) {
    int s = wave * 16 + si;
    const float* m = enc + ((size_t)s * B_ + b) * 512;
    float a = 0.f;
#pragma unroll
    for (int k = 0; k < 8; ++k) a += q[lane + k * 64] * m[lane + k * 64];
    for (int o = 32; o > 0; o >>= 1) a += __shfl_xor(a, o);
    if (lane == 0) al[s] = a;
  }
  __syncthreads();
  if (tid < 64) {
    float v = al[tid];
    float mx = v;
    for (int o = 32; o > 0; o >>= 1) mx = fmaxf(mx, __shfl_xor(mx, o));
    float e = expf(v - mx);
    float sm = e;
    for (int o = 32; o > 0; o >>= 1) sm += __shfl_xor(sm, o);
    al[tid] = e / sm;
  }
  __syncthreads();
  for (int d = tid; d < 512; d += 256) {
    float acc = 0.f;
#pragma unroll 16
    for (int s = 0; s < S_; ++s) acc += al[s] * enc[((size_t)s * B_ + b) * 512 + d];
    cat[(size_t)r * 1024 + d] = f2bf(acc);
  }
}

extern "C" void kernel_launch(void* const* d_in, const int* in_sizes, int n_in,
                              void* d_out, int out_size, void* d_ws, size_t ws_size,
                              hipStream_t stream) {
  const int* rnn = (const int*)d_in[0];
  const float* h0 = (const float*)d_in[1];
  const float* enc = (const float*)d_in[2];
  const float* tab = (const float*)d_in[3];
  const float* sruW = (const float*)d_in[4];
  const float* srub = (const float*)d_in[5];
  const float* attnW = (const float*)d_in[6];
  const float* outW = (const float*)d_in[7];
  const float* outb = (const float*)d_in[8];
  float* out = (float*)d_out;

  char* ws = (char*)d_ws;
  size_t off = 0;
  auto alloc = [&](size_t bytes) {
    char* p = ws + off;
    off += (bytes + 255) & ~(size_t)255;
    return p;
  };
  float* xf = (float*)alloc(4ull * 2048 * 512);
  float* xf2 = (float*)alloc(4ull * 2048 * 512);
  short* xb = (short*)alloc(2ull * 2048 * 512);
  float* U = (float*)alloc(4ull * 2048 * 1536);
  short* WTs = (short*)alloc(2ull * 2 * 1536 * 512);
  short* WTa = (short*)alloc(2ull * 512 * 1024);
  short* WTo = (short*)alloc(2ull * 32000 * 512);
  short* cat = (short*)alloc(2ull * 2048 * 1024);
  short* ah = (short*)alloc(2ull * 2048 * 512);

  // one fused prep kernel: 4 transposes + embed
  prep_kernel<<<22144, dim3(32, 8), 0, stream>>>(sruW, attnW, outW, rnn, tab,
                                                 WTs, WTa, WTo, xf, xb);

  float* hidden_out = out + (size_t)B_ * L_ * V_;

  // layer 0: x(=embed) -> h in xf2/xb   (64x128 tile, 384 blocks)
  gemm_t<64, 128, 1, 4, 0><<<384, 256, 0, stream>>>(xb, WTs, U, nullptr, 2048, 1536, 512, 32);
  sru_scan_kernel<<<256, 64, 0, stream>>>(U, srub, xf, h0, xf2, xb, hidden_out);
  // layer 1: h1 -> final h in xf/xb
  gemm_t<64, 128, 1, 4, 0><<<384, 256, 0, stream>>>(xb, WTs + 1536 * 512, U, nullptr,
                                                    2048, 1536, 512, 32);
  sru_scan_kernel<<<256, 64, 0, stream>>>(U, srub + 1024, xf2, h0 + B_ * D_, xf, xb,
                                          hidden_out + B_ * D_);

  // fused attention: scores+softmax+ctx+concat
  attn_fused_kernel<<<2048, 256, 0, stream>>>(xf, enc, xb, cat);

  // attn_h = tanh(concat @ attn_W) as bf16   (64x64 tile, 256 blocks)
  gemm_t<64, 64, 2, 2, 1><<<256, 256, 0, stream>>>(cat, WTa, ah, nullptr, 2048, 512, 1024, 32);
  // output = attn_h @ out_W + out_b, remapped to [B,L,V]  (128x128, 4000 blocks)
  gemm_t<128, 128, 2, 2, 2><<<4000, 256, 0, stream>>>(ah, WTo, out, outb, 2048, 32000, 512, 16);
}